// Round 21
// baseline (218.813 us; speedup 1.0000x reference)
//
#include <hip/hip_runtime.h>
#include <hip/hip_bf16.h>
#include <math.h>

#define Bz 131072
#define Dd 256

typedef __attribute__((ext_vector_type(8))) short short8;
typedef __attribute__((ext_vector_type(4))) float f32x4;
typedef __attribute__((ext_vector_type(4))) unsigned short u16x4;
typedef __attribute__((ext_vector_type(8))) unsigned short u16x8;

__device__ __forceinline__ unsigned short f2bf(float f) {
    union { __hip_bfloat16 h; unsigned short u; } v;
    v.h = __float2bfloat16(f);          // compiler emits optimal (pk-paired) cvt
    return v.u;
}
__device__ __forceinline__ float bf2f(unsigned short h) {
    union { unsigned int u; float f; } v; v.u = ((unsigned int)h) << 16;
    return v.f;
}
// tanh-form gelu: 0.5x(1+tanh(0.7978845608(x+0.044715x^3))), tanh via v_exp_f32 (2^x)
__device__ __forceinline__ float gelu_f(float x) {
    float u = 0.7978845608028654f * x * (1.0f + 0.044715f * x * x);
    float ex = __builtin_amdgcn_exp2f(u * 2.8853900817779268f);  // 2*log2(e)
    float th = 1.0f - 2.0f * __builtin_amdgcn_rcpf(1.0f + ex);
    return 0.5f * x * (1.0f + th);
}

#define MFMA16(a, b, c) __builtin_amdgcn_mfma_f32_16x16x32_bf16(a, b, c, 0, 0, 0)

// ctr layout (uint): [0..3] expert counts, [4..9] pair hist, [10..15] cursors, [16..22] bases
// ---------- prep: bf16-convert + transpose weights into stripe-linear layout.
__global__ __launch_bounds__(256) void prep_kernel(const float* __restrict__ W1,
                                                   const float* __restrict__ W2,
                                                   unsigned short* __restrict__ W1s,
                                                   unsigned short* __restrict__ W2s,
                                                   unsigned int* __restrict__ ctr) {
    __shared__ float tile[32][257];
    int bid = blockIdx.x;              // mat(2) x e(4) x tn(8) x q(4)
    int tid = threadIdx.x;
    if (bid == 0 && tid < 16) ctr[tid] = 0u;
    int mat = bid >> 7, e = (bid >> 5) & 3, tn = (bid >> 2) & 7, qq = bid & 3;
    const float* src = (mat ? W2 : W1) + e * 65536;
    unsigned short* dst = (mat ? W2s : W1s) + e * 65536 + tn * 8192;
#pragma unroll 4
    for (int kk = 0; kk < 32; ++kk)
        tile[kk][tid] = src[(tn * 32 + kk) * 256 + tid];
    __syncthreads();
#pragma unroll
    for (int oo = 0; oo < 8; ++oo) {
        int o = (qq * 8 + oo) * 256 + tid;     // quarter of 0..8191
        int u = o >> 11, c = (o >> 3) & 255, j = o & 7;
        dst[o] = f2bf(tile[u * 8 + j][c]);
    }
}

// ---------- gate v2: 16-lane groups, 4 rows in flight; dot-form f64 distances.
__global__ __launch_bounds__(256) void gate_kernel(const float* __restrict__ z,
                                                   const int* __restrict__ ridx_p,
                                                   const float* __restrict__ centroids,
                                                   const float* __restrict__ tau_raw,
                                                   float* __restrict__ wdense,
                                                   unsigned int* __restrict__ ctr) {
    __shared__ unsigned int scnt[4];
    __shared__ unsigned int shist[6];
    int tid = threadIdx.x;
    if (tid < 4) scnt[tid] = 0u;
    if (tid < 6) shist[tid] = 0u;
    __syncthreads();
    int lane = tid & 63;
    int l16 = lane & 15, grp = lane >> 4;
    int gwave = (blockIdx.x * 256 + tid) >> 6;         // 16 rows each
    int rbase = gwave * 16;
    int ridx = ridx_p[0];
    double tau = log1p(exp((double)tau_raw[ridx])) + 1e-6;
    const float* cb = centroids + (size_t)ridx * (4 * Dd);

    float c[4][16];
#pragma unroll
    for (int e = 0; e < 4; ++e)
#pragma unroll
        for (int q = 0; q < 4; ++q) {
            f32x4 cv = *(const f32x4*)(cb + e * 256 + l16 * 16 + q * 4);
#pragma unroll
            for (int j = 0; j < 4; ++j) c[e][q * 4 + j] = cv[j];
        }
    double cn[4];
#pragma unroll
    for (int e = 0; e < 4; ++e) {
        double s = 0.0;
#pragma unroll
        for (int j = 0; j < 16; ++j) {
            double cc = (double)c[e][j];
            s += cc * cc;
        }
#pragma unroll
        for (int m = 1; m < 16; m <<= 1) s += __shfl_xor(s, m, 64);
        cn[e] = s;
    }

    for (int it = 0; it < 4; ++it) {
        int row = rbase + it * 4 + grp;
        const float* zr = z + (size_t)row * 256 + l16 * 16;
        double dot[4] = {0.0, 0.0, 0.0, 0.0};
        double zn = 0.0;
#pragma unroll
        for (int q = 0; q < 4; ++q) {
            f32x4 zv = *(const f32x4*)(zr + q * 4);
#pragma unroll
            for (int j = 0; j < 4; ++j) {
                double zz = (double)zv[j];
                zn += zz * zz;
#pragma unroll
                for (int e = 0; e < 4; ++e)
                    dot[e] += zz * (double)c[e][q * 4 + j];
            }
        }
#pragma unroll
        for (int m = 1; m < 16; m <<= 1) {
            zn += __shfl_xor(zn, m, 64);
#pragma unroll
            for (int e = 0; e < 4; ++e) dot[e] += __shfl_xor(dot[e], m, 64);
        }
        if (l16 == 0) {
            double d2[4];
#pragma unroll
            for (int e = 0; e < 4; ++e) d2[e] = cn[e] - 2.0 * dot[e] + zn;
            int e1 = 0;
#pragma unroll
            for (int e = 1; e < 4; ++e) if (d2[e] < d2[e1]) e1 = e;
            int e2 = (e1 == 0) ? 1 : 0;
#pragma unroll
            for (int e = 0; e < 4; ++e)
                if (e != e1 && e != e2 && d2[e] < d2[e2]) e2 = e;
            double s1 = exp(-sqrt(d2[e1]) / tau);
            double s2 = exp(-sqrt(d2[e2]) / tau);
            double w1 = 1.0 / (1.0 + exp(s2 - s1));
            f32x4 wv;
#pragma unroll
            for (int j = 0; j < 4; ++j)
                wv[j] = (j == e1) ? (float)w1 : ((j == e2) ? (float)(1.0 - w1) : 0.0f);
            *(f32x4*)(wdense + (size_t)row * 4) = wv;
            int el = e1 < e2 ? e1 : e2;
            int eh = e1 < e2 ? e2 : e1;
            int pidx = (el == 0) ? (eh - 1) : ((el == 1) ? (eh + 1) : 5);
            atomicAdd(&shist[pidx], 1u);
            atomicAdd(&scnt[e1], 1u);
            atomicAdd(&scnt[e2], 1u);
        }
    }
    __syncthreads();
    if (tid < 4) atomicAdd(&ctr[tid], scnt[tid]);
    if (tid < 6) atomicAdd(&ctr[4 + tid], shist[tid]);
}

// ---------- offsets: 48-aligned bucket bases, zero cursors, fill padding slots
__global__ void offsets_kernel(unsigned int* __restrict__ ctr, int* __restrict__ perm) {
    __shared__ int sb[7], sh[6];
    int t = threadIdx.x;
    if (t == 0) {
        int base = 0;
        for (int p = 0; p < 6; ++p) {
            sb[p] = base;
            sh[p] = (int)ctr[4 + p];
            base += (sh[p] + 47) / 48 * 48;
        }
        sb[6] = base;
        for (int p = 0; p < 7; ++p) ctr[16 + p] = (unsigned int)sb[p];
    }
    if (t < 6) ctr[10 + t] = 0u;
    __syncthreads();
    for (int p = 0; p < 6; ++p)
        for (int s = sb[p] + sh[p] + t; s < sb[p + 1]; s += 64)
            perm[s] = -1;
}

// ---------- scatter: two-level (LDS histogram -> one range-reserve atomic per bucket per block)
__global__ __launch_bounds__(256) void scatter_kernel(const float* __restrict__ wdense,
                                                      unsigned int* __restrict__ ctr,
                                                      int* __restrict__ perm) {
    __shared__ unsigned int lcnt[6];
    __shared__ unsigned int lbase[6];
    int tid = threadIdx.x;
    if (tid < 6) lcnt[tid] = 0u;
    __syncthreads();
    int r = blockIdx.x * 256 + tid;
    f32x4 w = *(const f32x4*)(wdense + (size_t)r * 4);
    int el = -1, eh = -1;
#pragma unroll
    for (int e = 0; e < 4; ++e)
        if (w[e] != 0.0f) { if (el < 0) el = e; else eh = e; }
    int pidx = (el == 0) ? (eh - 1) : ((el == 1) ? (eh + 1) : 5);
    unsigned int local = atomicAdd(&lcnt[pidx], 1u);
    __syncthreads();
    if (tid < 6) lbase[tid] = atomicAdd(&ctr[10 + tid], lcnt[tid]);
    __syncthreads();
    perm[ctr[16 + pidx] + lbase[pidx] + local] = r;
}

// ---------- fused 2-expert FFN + combine + residual + LayerNorm
// 48-row tile, 8 waves; LN scratch overlaid into h1s; launch_bounds(512,6)
// caps unified regs at 85 -> 3 blocks/CU (24 waves). Prefetch distance 1
// (awc+awn only, -8 live regs) keeps demand ~80 under the cap without spill.
__global__ __launch_bounds__(512, 6) void ffn_kernel(const float* __restrict__ z,
    const unsigned short* __restrict__ W1s, const unsigned short* __restrict__ W2s,
    const float* __restrict__ b1, const float* __restrict__ b2,
    const float* __restrict__ wdense, const float* __restrict__ ln_g,
    const float* __restrict__ ln_b, const unsigned int* __restrict__ ctr,
    const int* __restrict__ perm, float* __restrict__ y) {
    __shared__ char zls[24576];        // Z tile bf16 (48 x 256); reused as h1sB
    __shared__ char h1s[24576];        // h1sA; later overlaid with LN scratch
    __shared__ int ridx_s[48];
    __shared__ float wa_s[48], wb_s[48];
    float* ps = (float*)h1s;           // [8][56] overlay (valid after GEMM2)
    float* pq = (float*)(h1s + 1792);  // [8][56]

    int slot0 = blockIdx.x * 48;
    int total = (int)ctr[22];
    if (slot0 >= total) return;
    int p = 0;
#pragma unroll
    for (int q = 1; q < 6; ++q) if (slot0 >= (int)ctr[16 + q]) p = q;
    int ea = (p < 3) ? 0 : ((p < 5) ? 1 : 2);
    int eb = (p < 3) ? (p + 1) : ((p < 5) ? (p - 1) : 3);

    int tid = threadIdx.x;
    int lane = tid & 63, wv = tid >> 6;
    int ln15 = lane & 15, lhi = lane >> 4;
    int l7 = ln15 & 7;
    int nbase = wv * 32;

    const unsigned short* g1a = W1s + (ea << 16);
    const unsigned short* g2a = W2s + (ea << 16);
    const unsigned short* g1b = W1s + (eb << 16);
    const unsigned short* g2b = W2s + (eb << 16);

    if (tid < 48) {
        int g = perm[slot0 + tid];
        ridx_s[tid] = g;
        int g2 = (g < 0) ? 0 : g;
        wa_s[tid] = wdense[(size_t)g2 * 4 + ea];
        wb_s[tid] = wdense[(size_t)g2 * 4 + eb];
    }
    __syncthreads();   // ridx_s visible

    // gather + stage Z -> bf16, slot-XOR swizzle (3 iters x 512 thr x 16B = 48x512B)
#pragma unroll
    for (int it = 0; it < 3; ++it) {
        int idx = it * 512 + tid;
        int r = idx >> 5, sl = idx & 31;
        int g = ridx_s[r]; if (g < 0) g = 0;
        f32x4 v0 = *(const f32x4*)(z + (size_t)g * 256 + sl * 8);
        f32x4 v1 = *(const f32x4*)(z + (size_t)g * 256 + sl * 8 + 4);
        u16x8 hv;
        hv[0] = f2bf(v0[0]); hv[1] = f2bf(v0[1]); hv[2] = f2bf(v0[2]); hv[3] = f2bf(v0[3]);
        hv[4] = f2bf(v1[0]); hv[5] = f2bf(v1[1]); hv[6] = f2bf(v1[2]); hv[7] = f2bf(v1[3]);
        *(u16x8*)(&zls[r * 512 + ((sl ^ (r & 7)) << 4)]) = hv;
    }
    __syncthreads();   // zls ready

    // residual z fragments -> registers (frees zls for reuse as h1sB later)
    u16x4 zrv[2][3];
#pragma unroll
    for (int fm = 0; fm < 2; ++fm) {
        int d0 = nbase + fm * 16 + lhi * 4;
        int dsl = d0 >> 3, db = (d0 & 7) * 2;
#pragma unroll
        for (int fn = 0; fn < 3; ++fn) {
            int row = fn * 16 + ln15;
            zrv[fm][fn] = *(const u16x4*)(&zls[row * 512 + ((dsl ^ (row & 7)) << 4) + db]);
        }
    }

    // per-thread invariant weight-fragment offset (elements) within a stripe
    int wfo = lhi * 2048 + (nbase + ln15) * 8;     // fm=0 ; fm=1 adds 128

    // one GEMM pass: 8 k-stripes, distance-1 aw prefetch, bv split loads
    auto gemm_phase = [&](const unsigned short* g0, const char* bsrc, f32x4 (&dst)[2][3]) {
        short8 a0c = *(const short8*)(g0 + wfo);
        short8 a1c = *(const short8*)(g0 + wfo + 128);
#pragma unroll
        for (int tn = 0; tn < 8; ++tn) {
            short8 a0n, a1n;
            if (tn < 7) {
                a0n = *(const short8*)(g0 + (tn + 1) * 8192 + wfo);
                a1n = *(const short8*)(g0 + (tn + 1) * 8192 + wfo + 128);
            }
            int sl = ((tn * 4 + lhi) ^ l7) << 4;
            {   // fn 0,1
                short8 bv0 = *(const short8*)(bsrc + (ln15) * 512 + sl);
                short8 bv1 = *(const short8*)(bsrc + (16 + ln15) * 512 + sl);
                __builtin_amdgcn_s_setprio(1);
                dst[0][0] = MFMA16(a0c, bv0, dst[0][0]);
                dst[1][0] = MFMA16(a1c, bv0, dst[1][0]);
                dst[0][1] = MFMA16(a0c, bv1, dst[0][1]);
                dst[1][1] = MFMA16(a1c, bv1, dst[1][1]);
                __builtin_amdgcn_s_setprio(0);
            }
            {   // fn 2
                short8 bv2 = *(const short8*)(bsrc + (32 + ln15) * 512 + sl);
                __builtin_amdgcn_s_setprio(1);
                dst[0][2] = MFMA16(a0c, bv2, dst[0][2]);
                dst[1][2] = MFMA16(a1c, bv2, dst[1][2]);
                __builtin_amdgcn_s_setprio(0);
            }
            if (tn < 7) { a0c = a0n; a1c = a1n; }
        }
    };

    {   // ---- phase 1: both GEMM1s (acc1 only live accumulator)
        f32x4 acc1[2][3];
        auto epi = [&](const float* b1e, const float* wsel, char* dst) {
#pragma unroll
            for (int fm = 0; fm < 2; ++fm) {
                int h0 = nbase + fm * 16 + lhi * 4;
                int hsl = h0 >> 3, hb = (h0 & 7) * 2;
                f32x4 b1f = *(const f32x4*)(b1e + h0);
#pragma unroll
                for (int fn = 0; fn < 3; ++fn) {
                    int row = fn * 16 + ln15;
                    float w = wsel[row];
                    u16x4 hv;
#pragma unroll
                    for (int i = 0; i < 4; ++i)
                        hv[i] = f2bf(gelu_f(acc1[fm][fn][i] + b1f[i]) * w);
                    *(u16x4*)(&dst[row * 512 + ((hsl ^ (row & 7)) << 4) + hb]) = hv;
                }
            }
        };
        // expert A: GEMM1A -> h1s
#pragma unroll
        for (int i = 0; i < 2; ++i)
#pragma unroll
            for (int j = 0; j < 3; ++j) acc1[i][j] = (f32x4)0.0f;
        gemm_phase(g1a, zls, acc1);
        epi(b1 + (ea << 8), wa_s, h1s);
        // expert B: GEMM1B (still reads zls)
#pragma unroll
        for (int i = 0; i < 2; ++i)
#pragma unroll
            for (int j = 0; j < 3; ++j) acc1[i][j] = (f32x4)0.0f;
        gemm_phase(g1b, zls, acc1);
        __syncthreads();               // all zls reads done; h1sA visible
        epi(b1 + (eb << 8), wb_s, zls);   // h1sB overwrites zls
        __syncthreads();               // h1sB visible
    }

    // ---- phase 2: combined GEMM2 (K=512) into acc (only live accumulator)
    f32x4 acc[2][3];
#pragma unroll
    for (int i = 0; i < 2; ++i)
#pragma unroll
        for (int j = 0; j < 3; ++j) acc[i][j] = (f32x4)0.0f;
    gemm_phase(g2a, h1s, acc);
    gemm_phase(g2b, zls, acc);
    __syncthreads();                   // all h1s reads done -> LN overlay may write

    // fold biases + residual (bf16 z from regs); per-row partial sums for LN
    float sA[3] = {0.0f, 0.0f, 0.0f};
    float sB[3] = {0.0f, 0.0f, 0.0f};
#pragma unroll
    for (int fm = 0; fm < 2; ++fm) {
        int d0 = nbase + fm * 16 + lhi * 4;
        f32x4 ba = *(const f32x4*)(b2 + (ea << 8) + d0);
        f32x4 bb = *(const f32x4*)(b2 + (eb << 8) + d0);
#pragma unroll
        for (int fn = 0; fn < 3; ++fn) {
            int row = fn * 16 + ln15;
            float wa = wa_s[row], wb = wb_s[row];
#pragma unroll
            for (int i = 0; i < 4; ++i) {
                float x = acc[fm][fn][i] + wa * ba[i] + wb * bb[i] + bf2f(zrv[fm][fn][i]);
                acc[fm][fn][i] = x;
                sA[fn] += x;
                sB[fn] += x * x;
            }
        }
    }
#pragma unroll
    for (int fn = 0; fn < 3; ++fn) {
        sA[fn] += __shfl_xor(sA[fn], 16, 64);
        sA[fn] += __shfl_xor(sA[fn], 32, 64);
        sB[fn] += __shfl_xor(sB[fn], 16, 64);
        sB[fn] += __shfl_xor(sB[fn], 32, 64);
    }
    if (lhi < 3) {
        float v1 = (lhi == 0) ? sA[0] : (lhi == 1) ? sA[1] : sA[2];
        float v2 = (lhi == 0) ? sB[0] : (lhi == 1) ? sB[1] : sB[2];
        int row = lhi * 16 + ln15;     // lane group lhi contributes fn = lhi
        ps[wv * 56 + row] = v1;
        pq[wv * 56 + row] = v2;
    }
    __syncthreads();

    float mu[3], rs[3];
#pragma unroll
    for (int fn = 0; fn < 3; ++fn) {
        int row = fn * 16 + ln15;
        float s = 0.0f, q = 0.0f;
#pragma unroll
        for (int j = 0; j < 8; ++j) { s += ps[j * 56 + row]; q += pq[j * 56 + row]; }
        float m = s * (1.0f / 256.0f);
        float var = q * (1.0f / 256.0f) - m * m;
        mu[fn] = m;
        rs[fn] = rsqrtf(var + 1e-5f);
    }
#pragma unroll
    for (int fm = 0; fm < 2; ++fm) {
        int d0 = nbase + fm * 16 + lhi * 4;
        f32x4 gm = *(const f32x4*)(ln_g + d0);
        f32x4 bt = *(const f32x4*)(ln_b + d0);
#pragma unroll
        for (int fn = 0; fn < 3; ++fn) {
            int row = fn * 16 + ln15;
            int g = ridx_s[row];
            if (g >= 0) {
                f32x4 yv;
#pragma unroll
                for (int i = 0; i < 4; ++i)
                    yv[i] = gm[i] * ((acc[fm][fn][i] - mu[fn]) * rs[fn]) + bt[i];
                *(f32x4*)(y + (size_t)g * 256 + d0) = yv;
            }
        }
    }
}

// ---------- finalize: expert utilization (exact /2^18)
__global__ void final_kernel(const unsigned int* __restrict__ ctr, float* __restrict__ out) {
    int t = threadIdx.x;
    if (t < 4) out[(size_t)Bz * Dd + t] = (float)ctr[t] * (1.0f / 262144.0f);
}

extern "C" void kernel_launch(void* const* d_in, const int* in_sizes, int n_in,
                              void* d_out, int out_size, void* d_ws, size_t ws_size,
                              hipStream_t stream) {
    const float* z         = (const float*)d_in[0];
    const int*   ridx      = (const int*)d_in[1];
    const float* centroids = (const float*)d_in[2];
    const float* tau_raw   = (const float*)d_in[3];
    const float* W1        = (const float*)d_in[4];
    const float* b1        = (const float*)d_in[5];
    const float* W2        = (const float*)d_in[6];
    const float* b2        = (const float*)d_in[7];
    const float* lng       = (const float*)d_in[8];
    const float* lnb       = (const float*)d_in[9];
    float* out = (float*)d_out;

    unsigned short* W1s    = (unsigned short*)d_ws;                          // 512 KB
    unsigned short* W2s    = (unsigned short*)((char*)d_ws + 524288);        // 512 KB
    float*          wdense = (float*)((char*)d_ws + 1048576);                // 2 MB
    int*            perm   = (int*)((char*)d_ws + 3145728);                  // ~515 KB
    unsigned int*   ctr    = (unsigned int*)((char*)d_ws + 3672064);         // 96 B

    hipLaunchKernelGGL(prep_kernel, dim3(256), dim3(256), 0, stream, W1, W2, W1s, W2s, ctr);
    hipLaunchKernelGGL(gate_kernel, dim3(2048), dim3(256), 0, stream, z, ridx, centroids, tau_raw, wdense, ctr);
    hipLaunchKernelGGL(offsets_kernel, dim3(1), dim3(64), 0, stream, ctr, perm);
    hipLaunchKernelGGL(scatter_kernel, dim3(512), dim3(256), 0, stream, wdense, ctr, perm);
    hipLaunchKernelGGL(ffn_kernel, dim3(2744), dim3(512), 0, stream, z, W1s, W2s, b1, b2, wdense, lng, lnb, ctr, perm, out);
    hipLaunchKernelGGL(final_kernel, dim3(1), dim3(64), 0, stream, ctr, out);
}

// Round 22
// 198.787 us; speedup vs baseline: 1.1007x; 1.1007x over previous
//
#include <hip/hip_runtime.h>
#include <hip/hip_bf16.h>
#include <math.h>

#define Bz 131072
#define Dd 256

typedef __attribute__((ext_vector_type(8))) short short8;
typedef __attribute__((ext_vector_type(4))) float f32x4;
typedef __attribute__((ext_vector_type(4))) unsigned short u16x4;
typedef __attribute__((ext_vector_type(8))) unsigned short u16x8;

__device__ __forceinline__ unsigned short f2bf(float f) {
    union { __hip_bfloat16 h; unsigned short u; } v;
    v.h = __float2bfloat16(f);
    return v.u;
}
__device__ __forceinline__ float bf2f(unsigned short h) {
    union { unsigned int u; float f; } v; v.u = ((unsigned int)h) << 16;
    return v.f;
}
// tanh-form gelu: 0.5x(1+tanh(0.7978845608(x+0.044715x^3))), tanh via v_exp_f32 (2^x)
__device__ __forceinline__ float gelu_f(float x) {
    float u = 0.7978845608028654f * x * (1.0f + 0.044715f * x * x);
    float ex = __builtin_amdgcn_exp2f(u * 2.8853900817779268f);  // 2*log2(e)
    float th = 1.0f - 2.0f * __builtin_amdgcn_rcpf(1.0f + ex);
    return 0.5f * x * (1.0f + th);
}

#define MFMA16(a, b, c) __builtin_amdgcn_mfma_f32_16x16x32_bf16(a, b, c, 0, 0, 0)

// ctr layout (uint): [0..3] expert counts, [4..9] pair hist, [10..15] cursors, [16..22] bases
// ---------- prep: bf16-convert + transpose weights into stripe-linear layout.
__global__ __launch_bounds__(256) void prep_kernel(const float* __restrict__ W1,
                                                   const float* __restrict__ W2,
                                                   unsigned short* __restrict__ W1s,
                                                   unsigned short* __restrict__ W2s,
                                                   unsigned int* __restrict__ ctr) {
    __shared__ float tile[32][257];
    int bid = blockIdx.x;              // mat(2) x e(4) x tn(8) x q(4)
    int tid = threadIdx.x;
    if (bid == 0 && tid < 16) ctr[tid] = 0u;
    int mat = bid >> 7, e = (bid >> 5) & 3, tn = (bid >> 2) & 7, qq = bid & 3;
    const float* src = (mat ? W2 : W1) + e * 65536;
    unsigned short* dst = (mat ? W2s : W1s) + e * 65536 + tn * 8192;
#pragma unroll 4
    for (int kk = 0; kk < 32; ++kk)
        tile[kk][tid] = src[(tn * 32 + kk) * 256 + tid];
    __syncthreads();
#pragma unroll
    for (int oo = 0; oo < 8; ++oo) {
        int o = (qq * 8 + oo) * 256 + tid;     // quarter of 0..8191
        int u = o >> 11, c = (o >> 3) & 255, j = o & 7;
        dst[o] = f2bf(tile[u * 8 + j][c]);
    }
}

// ---------- gate v2: 16-lane groups, 4 rows in flight; dot-form f64 distances.
// Also writes compact pair-index byte per row (for scatter).
__global__ __launch_bounds__(256) void gate_kernel(const float* __restrict__ z,
                                                   const int* __restrict__ ridx_p,
                                                   const float* __restrict__ centroids,
                                                   const float* __restrict__ tau_raw,
                                                   float* __restrict__ wdense,
                                                   unsigned char* __restrict__ prow,
                                                   unsigned int* __restrict__ ctr) {
    __shared__ unsigned int scnt[4];
    __shared__ unsigned int shist[6];
    int tid = threadIdx.x;
    if (tid < 4) scnt[tid] = 0u;
    if (tid < 6) shist[tid] = 0u;
    __syncthreads();
    int lane = tid & 63;
    int l16 = lane & 15, grp = lane >> 4;
    int gwave = (blockIdx.x * 256 + tid) >> 6;         // 16 rows each
    int rbase = gwave * 16;
    int ridx = ridx_p[0];
    double tau = log1p(exp((double)tau_raw[ridx])) + 1e-6;
    const float* cb = centroids + (size_t)ridx * (4 * Dd);

    float c[4][16];
#pragma unroll
    for (int e = 0; e < 4; ++e)
#pragma unroll
        for (int q = 0; q < 4; ++q) {
            f32x4 cv = *(const f32x4*)(cb + e * 256 + l16 * 16 + q * 4);
#pragma unroll
            for (int j = 0; j < 4; ++j) c[e][q * 4 + j] = cv[j];
        }
    double cn[4];
#pragma unroll
    for (int e = 0; e < 4; ++e) {
        double s = 0.0;
#pragma unroll
        for (int j = 0; j < 16; ++j) {
            double cc = (double)c[e][j];
            s += cc * cc;
        }
#pragma unroll
        for (int m = 1; m < 16; m <<= 1) s += __shfl_xor(s, m, 64);
        cn[e] = s;
    }

    for (int it = 0; it < 4; ++it) {
        int row = rbase + it * 4 + grp;
        const float* zr = z + (size_t)row * 256 + l16 * 16;
        double dot[4] = {0.0, 0.0, 0.0, 0.0};
        double zn = 0.0;
#pragma unroll
        for (int q = 0; q < 4; ++q) {
            f32x4 zv = *(const f32x4*)(zr + q * 4);
#pragma unroll
            for (int j = 0; j < 4; ++j) {
                double zz = (double)zv[j];
                zn += zz * zz;
#pragma unroll
                for (int e = 0; e < 4; ++e)
                    dot[e] += zz * (double)c[e][q * 4 + j];
            }
        }
#pragma unroll
        for (int m = 1; m < 16; m <<= 1) {
            zn += __shfl_xor(zn, m, 64);
#pragma unroll
            for (int e = 0; e < 4; ++e) dot[e] += __shfl_xor(dot[e], m, 64);
        }
        if (l16 == 0) {
            double d2[4];
#pragma unroll
            for (int e = 0; e < 4; ++e) d2[e] = cn[e] - 2.0 * dot[e] + zn;
            int e1 = 0;
#pragma unroll
            for (int e = 1; e < 4; ++e) if (d2[e] < d2[e1]) e1 = e;
            int e2 = (e1 == 0) ? 1 : 0;
#pragma unroll
            for (int e = 0; e < 4; ++e)
                if (e != e1 && e != e2 && d2[e] < d2[e2]) e2 = e;
            double s1 = exp(-sqrt(d2[e1]) / tau);
            double s2 = exp(-sqrt(d2[e2]) / tau);
            double w1 = 1.0 / (1.0 + exp(s2 - s1));
            f32x4 wv;
#pragma unroll
            for (int j = 0; j < 4; ++j)
                wv[j] = (j == e1) ? (float)w1 : ((j == e2) ? (float)(1.0 - w1) : 0.0f);
            *(f32x4*)(wdense + (size_t)row * 4) = wv;
            int el = e1 < e2 ? e1 : e2;
            int eh = e1 < e2 ? e2 : e1;
            int pidx = (el == 0) ? (eh - 1) : ((el == 1) ? (eh + 1) : 5);
            prow[row] = (unsigned char)pidx;
            atomicAdd(&shist[pidx], 1u);
            atomicAdd(&scnt[e1], 1u);
            atomicAdd(&scnt[e2], 1u);
        }
    }
    __syncthreads();
    if (tid < 4) atomicAdd(&ctr[tid], scnt[tid]);
    if (tid < 6) atomicAdd(&ctr[4 + tid], shist[tid]);
}

// ---------- offsets: 48-aligned bucket bases, zero cursors, fill padding slots,
// and emit expert-utilization tail (counts are final after gate).
__global__ void offsets_kernel(unsigned int* __restrict__ ctr, int* __restrict__ perm,
                               float* __restrict__ out) {
    __shared__ int sb[7], sh[6];
    int t = threadIdx.x;
    if (t == 0) {
        int base = 0;
        for (int p = 0; p < 6; ++p) {
            sb[p] = base;
            sh[p] = (int)ctr[4 + p];
            base += (sh[p] + 47) / 48 * 48;
        }
        sb[6] = base;
        for (int p = 0; p < 7; ++p) ctr[16 + p] = (unsigned int)sb[p];
    }
    if (t < 6) ctr[10 + t] = 0u;
    if (t >= 8 && t < 12) out[(size_t)Bz * Dd + (t - 8)] = (float)ctr[t - 8] * (1.0f / 262144.0f);
    __syncthreads();
    for (int p = 0; p < 6; ++p)
        for (int s = sb[p] + sh[p] + t; s < sb[p + 1]; s += 64)
            perm[s] = -1;
}

// ---------- scatter: two-level, reads compact pair-index bytes
__global__ __launch_bounds__(256) void scatter_kernel(const unsigned char* __restrict__ prow,
                                                      unsigned int* __restrict__ ctr,
                                                      int* __restrict__ perm) {
    __shared__ unsigned int lcnt[6];
    __shared__ unsigned int lbase[6];
    int tid = threadIdx.x;
    if (tid < 6) lcnt[tid] = 0u;
    __syncthreads();
    int r = blockIdx.x * 256 + tid;
    int pidx = prow[r];
    unsigned int local = atomicAdd(&lcnt[pidx], 1u);
    __syncthreads();
    if (tid < 6) lbase[tid] = atomicAdd(&ctr[10 + tid], lcnt[tid]);
    __syncthreads();
    perm[ctr[16 + pidx] + lbase[pidx] + local] = r;
}

// ---------- fused 2-expert FFN + combine + residual + LayerNorm (R19 best config)
// 48-row tile, 8 waves; (512,4): 2 blocks/CU spill-free (measured best vs 3-block+spill).
__global__ __launch_bounds__(512, 4) void ffn_kernel(const float* __restrict__ z,
    const unsigned short* __restrict__ W1s, const unsigned short* __restrict__ W2s,
    const float* __restrict__ b1, const float* __restrict__ b2,
    const float* __restrict__ wdense, const float* __restrict__ ln_g,
    const float* __restrict__ ln_b, const unsigned int* __restrict__ ctr,
    const int* __restrict__ perm, float* __restrict__ y) {
    __shared__ char zls[24576];        // Z tile bf16 (48 x 256); reused as h1sB
    __shared__ char h1s[24576];        // h1sA, slot-XOR swizzle
    __shared__ int ridx_s[48];
    __shared__ float wa_s[48], wb_s[48];
    __shared__ float ps[8][56], pq[8][56];   // transposed: conflict-free LN reduce

    int slot0 = blockIdx.x * 48;
    int total = (int)ctr[22];
    if (slot0 >= total) return;
    int p = 0;
#pragma unroll
    for (int q = 1; q < 6; ++q) if (slot0 >= (int)ctr[16 + q]) p = q;
    int ea = (p < 3) ? 0 : ((p < 5) ? 1 : 2);
    int eb = (p < 3) ? (p + 1) : ((p < 5) ? (p - 1) : 3);

    int tid = threadIdx.x;
    int lane = tid & 63, wv = tid >> 6;
    int ln15 = lane & 15, lhi = lane >> 4;
    int l7 = ln15 & 7;
    int nbase = wv * 32;

    const unsigned short* g1a = W1s + (ea << 16);
    const unsigned short* g2a = W2s + (ea << 16);
    const unsigned short* g1b = W1s + (eb << 16);
    const unsigned short* g2b = W2s + (eb << 16);

    if (tid < 48) {
        int g = perm[slot0 + tid];
        ridx_s[tid] = g;
        int g2 = (g < 0) ? 0 : g;
        wa_s[tid] = wdense[(size_t)g2 * 4 + ea];
        wb_s[tid] = wdense[(size_t)g2 * 4 + eb];
    }
    __syncthreads();   // ridx_s visible

    // gather + stage Z -> bf16, slot-XOR swizzle (3 iters x 512 thr x 16B = 48x512B)
#pragma unroll
    for (int it = 0; it < 3; ++it) {
        int idx = it * 512 + tid;
        int r = idx >> 5, sl = idx & 31;
        int g = ridx_s[r]; if (g < 0) g = 0;
        f32x4 v0 = *(const f32x4*)(z + (size_t)g * 256 + sl * 8);
        f32x4 v1 = *(const f32x4*)(z + (size_t)g * 256 + sl * 8 + 4);
        u16x8 hv;
        hv[0] = f2bf(v0[0]); hv[1] = f2bf(v0[1]); hv[2] = f2bf(v0[2]); hv[3] = f2bf(v0[3]);
        hv[4] = f2bf(v1[0]); hv[5] = f2bf(v1[1]); hv[6] = f2bf(v1[2]); hv[7] = f2bf(v1[3]);
        *(u16x8*)(&zls[r * 512 + ((sl ^ (r & 7)) << 4)]) = hv;
    }
    __syncthreads();   // zls ready

    // residual z fragments -> registers (frees zls for reuse as h1sB later)
    u16x4 zrv[2][3];
#pragma unroll
    for (int fm = 0; fm < 2; ++fm) {
        int d0 = nbase + fm * 16 + lhi * 4;
        int dsl = d0 >> 3, db = (d0 & 7) * 2;
#pragma unroll
        for (int fn = 0; fn < 3; ++fn) {
            int row = fn * 16 + ln15;
            zrv[fm][fn] = *(const u16x4*)(&zls[row * 512 + ((dsl ^ (row & 7)) << 4) + db]);
        }
    }

    // per-thread invariant weight-fragment offset (elements) within a stripe
    int wfo = lhi * 2048 + (nbase + ln15) * 8;     // fm=0 ; fm=1 adds 128

    // one GEMM pass: 8 k-stripes, rolling distance-2 aw prefetch, bv split loads
    auto gemm_phase = [&](const unsigned short* g0, const char* bsrc, f32x4 (&dst)[2][3]) {
        short8 a0c = *(const short8*)(g0 + wfo);
        short8 a1c = *(const short8*)(g0 + wfo + 128);
        short8 a0m = *(const short8*)(g0 + 8192 + wfo);
        short8 a1m = *(const short8*)(g0 + 8192 + wfo + 128);
#pragma unroll
        for (int tn = 0; tn < 8; ++tn) {
            short8 a0n, a1n;
            if (tn < 6) {
                a0n = *(const short8*)(g0 + (tn + 2) * 8192 + wfo);
                a1n = *(const short8*)(g0 + (tn + 2) * 8192 + wfo + 128);
            }
            int sl = ((tn * 4 + lhi) ^ l7) << 4;
            {   // fn 0,1
                short8 bv0 = *(const short8*)(bsrc + (ln15) * 512 + sl);
                short8 bv1 = *(const short8*)(bsrc + (16 + ln15) * 512 + sl);
                __builtin_amdgcn_s_setprio(1);
                dst[0][0] = MFMA16(a0c, bv0, dst[0][0]);
                dst[1][0] = MFMA16(a1c, bv0, dst[1][0]);
                dst[0][1] = MFMA16(a0c, bv1, dst[0][1]);
                dst[1][1] = MFMA16(a1c, bv1, dst[1][1]);
                __builtin_amdgcn_s_setprio(0);
            }
            {   // fn 2
                short8 bv2 = *(const short8*)(bsrc + (32 + ln15) * 512 + sl);
                __builtin_amdgcn_s_setprio(1);
                dst[0][2] = MFMA16(a0c, bv2, dst[0][2]);
                dst[1][2] = MFMA16(a1c, bv2, dst[1][2]);
                __builtin_amdgcn_s_setprio(0);
            }
            a0c = a0m; a1c = a1m;
            if (tn < 6) { a0m = a0n; a1m = a1n; }
        }
    };

    {   // ---- phase 1: both GEMM1s (acc1 only live accumulator)
        f32x4 acc1[2][3];
        auto epi = [&](const float* b1e, const float* wsel, char* dst) {
#pragma unroll
            for (int fm = 0; fm < 2; ++fm) {
                int h0 = nbase + fm * 16 + lhi * 4;
                int hsl = h0 >> 3, hb = (h0 & 7) * 2;
                f32x4 b1f = *(const f32x4*)(b1e + h0);
#pragma unroll
                for (int fn = 0; fn < 3; ++fn) {
                    int row = fn * 16 + ln15;
                    float w = wsel[row];
                    u16x4 hv;
#pragma unroll
                    for (int i = 0; i < 4; ++i)
                        hv[i] = f2bf(gelu_f(acc1[fm][fn][i] + b1f[i]) * w);
                    *(u16x4*)(&dst[row * 512 + ((hsl ^ (row & 7)) << 4) + hb]) = hv;
                }
            }
        };
        // expert A: GEMM1A -> h1s
#pragma unroll
        for (int i = 0; i < 2; ++i)
#pragma unroll
            for (int j = 0; j < 3; ++j) acc1[i][j] = (f32x4)0.0f;
        gemm_phase(g1a, zls, acc1);
        epi(b1 + (ea << 8), wa_s, h1s);
        // expert B: GEMM1B (still reads zls)
#pragma unroll
        for (int i = 0; i < 2; ++i)
#pragma unroll
            for (int j = 0; j < 3; ++j) acc1[i][j] = (f32x4)0.0f;
        gemm_phase(g1b, zls, acc1);
        __syncthreads();               // all zls reads done; h1sA visible
        epi(b1 + (eb << 8), wb_s, zls);   // h1sB overwrites zls
        __syncthreads();               // h1sB visible
    }

    // ---- phase 2: combined GEMM2 (K=512) into acc (only live accumulator)
    f32x4 acc[2][3];
#pragma unroll
    for (int i = 0; i < 2; ++i)
#pragma unroll
        for (int j = 0; j < 3; ++j) acc[i][j] = (f32x4)0.0f;
    gemm_phase(g2a, h1s, acc);
    gemm_phase(g2b, zls, acc);

    // fold biases + residual (bf16 z from regs); per-row partial sums for LN
    float sA[3] = {0.0f, 0.0f, 0.0f};
    float sB[3] = {0.0f, 0.0f, 0.0f};
#pragma unroll
    for (int fm = 0; fm < 2; ++fm) {
        int d0 = nbase + fm * 16 + lhi * 4;
        f32x4 ba = *(const f32x4*)(b2 + (ea << 8) + d0);
        f32x4 bb = *(const f32x4*)(b2 + (eb << 8) + d0);
#pragma unroll
        for (int fn = 0; fn < 3; ++fn) {
            int row = fn * 16 + ln15;
            float wa = wa_s[row], wb = wb_s[row];
#pragma unroll
            for (int i = 0; i < 4; ++i) {
                float x = acc[fm][fn][i] + wa * ba[i] + wb * bb[i] + bf2f(zrv[fm][fn][i]);
                acc[fm][fn][i] = x;
                sA[fn] += x;
                sB[fn] += x * x;
            }
        }
    }
#pragma unroll
    for (int fn = 0; fn < 3; ++fn) {
        sA[fn] += __shfl_xor(sA[fn], 16, 64);
        sA[fn] += __shfl_xor(sA[fn], 32, 64);
        sB[fn] += __shfl_xor(sB[fn], 16, 64);
        sB[fn] += __shfl_xor(sB[fn], 32, 64);
    }
    if (lhi < 3) {
        float v1 = (lhi == 0) ? sA[0] : (lhi == 1) ? sA[1] : sA[2];
        float v2 = (lhi == 0) ? sB[0] : (lhi == 1) ? sB[1] : sB[2];
        int row = lhi * 16 + ln15;     // lane group lhi contributes fn = lhi
        ps[wv][row] = v1;
        pq[wv][row] = v2;
    }
    __syncthreads();

    float mu[3], rs[3];
#pragma unroll
    for (int fn = 0; fn < 3; ++fn) {
        int row = fn * 16 + ln15;
        float s = 0.0f, q = 0.0f;
#pragma unroll
        for (int j = 0; j < 8; ++j) { s += ps[j][row]; q += pq[j][row]; }
        float m = s * (1.0f / 256.0f);
        float var = q * (1.0f / 256.0f) - m * m;
        mu[fn] = m;
        rs[fn] = rsqrtf(var + 1e-5f);
    }
#pragma unroll
    for (int fm = 0; fm < 2; ++fm) {
        int d0 = nbase + fm * 16 + lhi * 4;
        f32x4 gm = *(const f32x4*)(ln_g + d0);
        f32x4 bt = *(const f32x4*)(ln_b + d0);
#pragma unroll
        for (int fn = 0; fn < 3; ++fn) {
            int row = fn * 16 + ln15;
            int g = ridx_s[row];
            if (g >= 0) {
                f32x4 yv;
#pragma unroll
                for (int i = 0; i < 4; ++i)
                    yv[i] = gm[i] * ((acc[fm][fn][i] - mu[fn]) * rs[fn]) + bt[i];
                *(f32x4*)(y + (size_t)g * 256 + d0) = yv;
            }
        }
    }
}

extern "C" void kernel_launch(void* const* d_in, const int* in_sizes, int n_in,
                              void* d_out, int out_size, void* d_ws, size_t ws_size,
                              hipStream_t stream) {
    const float* z         = (const float*)d_in[0];
    const int*   ridx      = (const int*)d_in[1];
    const float* centroids = (const float*)d_in[2];
    const float* tau_raw   = (const float*)d_in[3];
    const float* W1        = (const float*)d_in[4];
    const float* b1        = (const float*)d_in[5];
    const float* W2        = (const float*)d_in[6];
    const float* b2        = (const float*)d_in[7];
    const float* lng       = (const float*)d_in[8];
    const float* lnb       = (const float*)d_in[9];
    float* out = (float*)d_out;

    unsigned short* W1s    = (unsigned short*)d_ws;                          // 512 KB
    unsigned short* W2s    = (unsigned short*)((char*)d_ws + 524288);        // 512 KB
    float*          wdense = (float*)((char*)d_ws + 1048576);                // 2 MB
    int*            perm   = (int*)((char*)d_ws + 3145728);                  // ~515 KB
    unsigned int*   ctr    = (unsigned int*)((char*)d_ws + 3672064);         // 96 B
    unsigned char*  prow   = (unsigned char*)((char*)d_ws + 3673088);        // 128 KB

    hipLaunchKernelGGL(prep_kernel, dim3(256), dim3(256), 0, stream, W1, W2, W1s, W2s, ctr);
    hipLaunchKernelGGL(gate_kernel, dim3(2048), dim3(256), 0, stream, z, ridx, centroids, tau_raw, wdense, prow, ctr);
    hipLaunchKernelGGL(offsets_kernel, dim3(1), dim3(64), 0, stream, ctr, perm, out);
    hipLaunchKernelGGL(scatter_kernel, dim3(512), dim3(256), 0, stream, prow, ctr, perm);
    hipLaunchKernelGGL(ffn_kernel, dim3(2744), dim3(512), 0, stream, z, W1s, W2s, b1, b2, wdense, lng, lnb, ctr, perm, out);
}

// Round 23
// 191.855 us; speedup vs baseline: 1.1405x; 1.0361x over previous
//
#include <hip/hip_runtime.h>
#include <hip/hip_bf16.h>
#include <math.h>

#define Bz 131072
#define Dd 256

typedef __attribute__((ext_vector_type(8))) short short8;
typedef __attribute__((ext_vector_type(4))) float f32x4;
typedef __attribute__((ext_vector_type(4))) unsigned short u16x4;
typedef __attribute__((ext_vector_type(8))) unsigned short u16x8;

__device__ __forceinline__ unsigned short f2bf(float f) {
    union { __hip_bfloat16 h; unsigned short u; } v;
    v.h = __float2bfloat16(f);
    return v.u;
}
__device__ __forceinline__ float bf2f(unsigned short h) {
    union { unsigned int u; float f; } v; v.u = ((unsigned int)h) << 16;
    return v.f;
}
// tanh-form gelu: 0.5x(1+tanh(0.7978845608(x+0.044715x^3))), tanh via v_exp_f32 (2^x)
__device__ __forceinline__ float gelu_f(float x) {
    float u = 0.7978845608028654f * x * (1.0f + 0.044715f * x * x);
    float ex = __builtin_amdgcn_exp2f(u * 2.8853900817779268f);  // 2*log2(e)
    float th = 1.0f - 2.0f * __builtin_amdgcn_rcpf(1.0f + ex);
    return 0.5f * x * (1.0f + th);
}

#define MFMA16(a, b, c) __builtin_amdgcn_mfma_f32_16x16x32_bf16(a, b, c, 0, 0, 0)

// ctr layout (uint): [0..3] expert counts, [4..9] pair hist, [10..15] cursors, [16..22] bases
// ---------- prep: bf16-convert + transpose weights into stripe-linear layout.
__global__ __launch_bounds__(256) void prep_kernel(const float* __restrict__ W1,
                                                   const float* __restrict__ W2,
                                                   unsigned short* __restrict__ W1s,
                                                   unsigned short* __restrict__ W2s,
                                                   unsigned int* __restrict__ ctr) {
    __shared__ float tile[32][257];
    int bid = blockIdx.x;              // mat(2) x e(4) x tn(8) x q(4)
    int tid = threadIdx.x;
    if (bid == 0 && tid < 16) ctr[tid] = 0u;
    int mat = bid >> 7, e = (bid >> 5) & 3, tn = (bid >> 2) & 7, qq = bid & 3;
    const float* src = (mat ? W2 : W1) + e * 65536;
    unsigned short* dst = (mat ? W2s : W1s) + e * 65536 + tn * 8192;
#pragma unroll 4
    for (int kk = 0; kk < 32; ++kk)
        tile[kk][tid] = src[(tn * 32 + kk) * 256 + tid];
    __syncthreads();
#pragma unroll
    for (int oo = 0; oo < 8; ++oo) {
        int o = (qq * 8 + oo) * 256 + tid;     // quarter of 0..8191
        int u = o >> 11, c = (o >> 3) & 255, j = o & 7;
        dst[o] = f2bf(tile[u * 8 + j][c]);
    }
}

// ---------- gate v2: 16-lane groups, 4 rows in flight; dot-form f64 distances.
__global__ __launch_bounds__(256) void gate_kernel(const float* __restrict__ z,
                                                   const int* __restrict__ ridx_p,
                                                   const float* __restrict__ centroids,
                                                   const float* __restrict__ tau_raw,
                                                   float* __restrict__ wdense,
                                                   unsigned char* __restrict__ prow,
                                                   unsigned int* __restrict__ ctr) {
    __shared__ unsigned int scnt[4];
    __shared__ unsigned int shist[6];
    int tid = threadIdx.x;
    if (tid < 4) scnt[tid] = 0u;
    if (tid < 6) shist[tid] = 0u;
    __syncthreads();
    int lane = tid & 63;
    int l16 = lane & 15, grp = lane >> 4;
    int gwave = (blockIdx.x * 256 + tid) >> 6;         // 16 rows each
    int rbase = gwave * 16;
    int ridx = ridx_p[0];
    double tau = log1p(exp((double)tau_raw[ridx])) + 1e-6;
    const float* cb = centroids + (size_t)ridx * (4 * Dd);

    float c[4][16];
#pragma unroll
    for (int e = 0; e < 4; ++e)
#pragma unroll
        for (int q = 0; q < 4; ++q) {
            f32x4 cv = *(const f32x4*)(cb + e * 256 + l16 * 16 + q * 4);
#pragma unroll
            for (int j = 0; j < 4; ++j) c[e][q * 4 + j] = cv[j];
        }
    double cn[4];
#pragma unroll
    for (int e = 0; e < 4; ++e) {
        double s = 0.0;
#pragma unroll
        for (int j = 0; j < 16; ++j) {
            double cc = (double)c[e][j];
            s += cc * cc;
        }
#pragma unroll
        for (int m = 1; m < 16; m <<= 1) s += __shfl_xor(s, m, 64);
        cn[e] = s;
    }

    for (int it = 0; it < 4; ++it) {
        int row = rbase + it * 4 + grp;
        const float* zr = z + (size_t)row * 256 + l16 * 16;
        double dot[4] = {0.0, 0.0, 0.0, 0.0};
        double zn = 0.0;
#pragma unroll
        for (int q = 0; q < 4; ++q) {
            f32x4 zv = *(const f32x4*)(zr + q * 4);
#pragma unroll
            for (int j = 0; j < 4; ++j) {
                double zz = (double)zv[j];
                zn += zz * zz;
#pragma unroll
                for (int e = 0; e < 4; ++e)
                    dot[e] += zz * (double)c[e][q * 4 + j];
            }
        }
#pragma unroll
        for (int m = 1; m < 16; m <<= 1) {
            zn += __shfl_xor(zn, m, 64);
#pragma unroll
            for (int e = 0; e < 4; ++e) dot[e] += __shfl_xor(dot[e], m, 64);
        }
        if (l16 == 0) {
            double d2[4];
#pragma unroll
            for (int e = 0; e < 4; ++e) d2[e] = cn[e] - 2.0 * dot[e] + zn;
            int e1 = 0;
#pragma unroll
            for (int e = 1; e < 4; ++e) if (d2[e] < d2[e1]) e1 = e;
            int e2 = (e1 == 0) ? 1 : 0;
#pragma unroll
            for (int e = 0; e < 4; ++e)
                if (e != e1 && e != e2 && d2[e] < d2[e2]) e2 = e;
            double s1 = exp(-sqrt(d2[e1]) / tau);
            double s2 = exp(-sqrt(d2[e2]) / tau);
            double w1 = 1.0 / (1.0 + exp(s2 - s1));
            f32x4 wv;
#pragma unroll
            for (int j = 0; j < 4; ++j)
                wv[j] = (j == e1) ? (float)w1 : ((j == e2) ? (float)(1.0 - w1) : 0.0f);
            *(f32x4*)(wdense + (size_t)row * 4) = wv;
            int el = e1 < e2 ? e1 : e2;
            int eh = e1 < e2 ? e2 : e1;
            int pidx = (el == 0) ? (eh - 1) : ((el == 1) ? (eh + 1) : 5);
            prow[row] = (unsigned char)pidx;
            atomicAdd(&shist[pidx], 1u);
            atomicAdd(&scnt[e1], 1u);
            atomicAdd(&scnt[e2], 1u);
        }
    }
    __syncthreads();
    if (tid < 4) atomicAdd(&ctr[tid], scnt[tid]);
    if (tid < 6) atomicAdd(&ctr[4 + tid], shist[tid]);
}

// ---------- offsets: 48-aligned bucket bases, zero cursors, fill padding slots,
// and emit expert-utilization tail (counts are final after gate).
__global__ void offsets_kernel(unsigned int* __restrict__ ctr, int* __restrict__ perm,
                               float* __restrict__ out) {
    __shared__ int sb[7], sh[6];
    int t = threadIdx.x;
    if (t == 0) {
        int base = 0;
        for (int p = 0; p < 6; ++p) {
            sb[p] = base;
            sh[p] = (int)ctr[4 + p];
            base += (sh[p] + 47) / 48 * 48;
        }
        sb[6] = base;
        for (int p = 0; p < 7; ++p) ctr[16 + p] = (unsigned int)sb[p];
    }
    if (t < 6) ctr[10 + t] = 0u;
    if (t >= 8 && t < 12) out[(size_t)Bz * Dd + (t - 8)] = (float)ctr[t - 8] * (1.0f / 262144.0f);
    __syncthreads();
    for (int p = 0; p < 6; ++p)
        for (int s = sb[p] + sh[p] + t; s < sb[p + 1]; s += 64)
            perm[s] = -1;
}

// ---------- scatter: two-level, reads compact pair-index bytes
__global__ __launch_bounds__(256) void scatter_kernel(const unsigned char* __restrict__ prow,
                                                      unsigned int* __restrict__ ctr,
                                                      int* __restrict__ perm) {
    __shared__ unsigned int lcnt[6];
    __shared__ unsigned int lbase[6];
    int tid = threadIdx.x;
    if (tid < 6) lcnt[tid] = 0u;
    __syncthreads();
    int r = blockIdx.x * 256 + tid;
    int pidx = prow[r];
    unsigned int local = atomicAdd(&lcnt[pidx], 1u);
    __syncthreads();
    if (tid < 6) lbase[tid] = atomicAdd(&ctr[10 + tid], lcnt[tid]);
    __syncthreads();
    perm[ctr[16 + pidx] + lbase[pidx] + local] = r;
}

// ---------- fused 2-expert FFN + combine + residual + LayerNorm (best config)
// 48-row tile, 8 waves; (512,4): 2 blocks/CU spill-free. Non-temporal z loads
// (read-once gathered rows) and y stores (write-once) keep L2 for weights.
__global__ __launch_bounds__(512, 4) void ffn_kernel(const float* __restrict__ z,
    const unsigned short* __restrict__ W1s, const unsigned short* __restrict__ W2s,
    const float* __restrict__ b1, const float* __restrict__ b2,
    const float* __restrict__ wdense, const float* __restrict__ ln_g,
    const float* __restrict__ ln_b, const unsigned int* __restrict__ ctr,
    const int* __restrict__ perm, float* __restrict__ y) {
    __shared__ char zls[24576];        // Z tile bf16 (48 x 256); reused as h1sB
    __shared__ char h1s[24576];        // h1sA, slot-XOR swizzle
    __shared__ int ridx_s[48];
    __shared__ float wa_s[48], wb_s[48];
    __shared__ float ps[8][56], pq[8][56];   // transposed: conflict-free LN reduce

    int slot0 = blockIdx.x * 48;
    int total = (int)ctr[22];
    if (slot0 >= total) return;
    int p = 0;
#pragma unroll
    for (int q = 1; q < 6; ++q) if (slot0 >= (int)ctr[16 + q]) p = q;
    int ea = (p < 3) ? 0 : ((p < 5) ? 1 : 2);
    int eb = (p < 3) ? (p + 1) : ((p < 5) ? (p - 1) : 3);

    int tid = threadIdx.x;
    int lane = tid & 63, wv = tid >> 6;
    int ln15 = lane & 15, lhi = lane >> 4;
    int l7 = ln15 & 7;
    int nbase = wv * 32;

    const unsigned short* g1a = W1s + (ea << 16);
    const unsigned short* g2a = W2s + (ea << 16);
    const unsigned short* g1b = W1s + (eb << 16);
    const unsigned short* g2b = W2s + (eb << 16);

    if (tid < 48) {
        int g = perm[slot0 + tid];
        ridx_s[tid] = g;
        int g2 = (g < 0) ? 0 : g;
        wa_s[tid] = wdense[(size_t)g2 * 4 + ea];
        wb_s[tid] = wdense[(size_t)g2 * 4 + eb];
    }
    __syncthreads();   // ridx_s visible

    // gather + stage Z -> bf16, slot-XOR swizzle (3 iters x 512 thr x 16B = 48x512B)
#pragma unroll
    for (int it = 0; it < 3; ++it) {
        int idx = it * 512 + tid;
        int r = idx >> 5, sl = idx & 31;
        int g = ridx_s[r]; if (g < 0) g = 0;
        f32x4 v0 = __builtin_nontemporal_load((const f32x4*)(z + (size_t)g * 256 + sl * 8));
        f32x4 v1 = __builtin_nontemporal_load((const f32x4*)(z + (size_t)g * 256 + sl * 8 + 4));
        u16x8 hv;
        hv[0] = f2bf(v0[0]); hv[1] = f2bf(v0[1]); hv[2] = f2bf(v0[2]); hv[3] = f2bf(v0[3]);
        hv[4] = f2bf(v1[0]); hv[5] = f2bf(v1[1]); hv[6] = f2bf(v1[2]); hv[7] = f2bf(v1[3]);
        *(u16x8*)(&zls[r * 512 + ((sl ^ (r & 7)) << 4)]) = hv;
    }
    __syncthreads();   // zls ready

    // residual z fragments -> registers (frees zls for reuse as h1sB later)
    u16x4 zrv[2][3];
#pragma unroll
    for (int fm = 0; fm < 2; ++fm) {
        int d0 = nbase + fm * 16 + lhi * 4;
        int dsl = d0 >> 3, db = (d0 & 7) * 2;
#pragma unroll
        for (int fn = 0; fn < 3; ++fn) {
            int row = fn * 16 + ln15;
            zrv[fm][fn] = *(const u16x4*)(&zls[row * 512 + ((dsl ^ (row & 7)) << 4) + db]);
        }
    }

    // per-thread invariant weight-fragment offset (elements) within a stripe
    int wfo = lhi * 2048 + (nbase + ln15) * 8;     // fm=0 ; fm=1 adds 128

    // one GEMM pass: 8 k-stripes, rolling distance-2 aw prefetch, bv split loads
    auto gemm_phase = [&](const unsigned short* g0, const char* bsrc, f32x4 (&dst)[2][3]) {
        short8 a0c = *(const short8*)(g0 + wfo);
        short8 a1c = *(const short8*)(g0 + wfo + 128);
        short8 a0m = *(const short8*)(g0 + 8192 + wfo);
        short8 a1m = *(const short8*)(g0 + 8192 + wfo + 128);
#pragma unroll
        for (int tn = 0; tn < 8; ++tn) {
            short8 a0n, a1n;
            if (tn < 6) {
                a0n = *(const short8*)(g0 + (tn + 2) * 8192 + wfo);
                a1n = *(const short8*)(g0 + (tn + 2) * 8192 + wfo + 128);
            }
            int sl = ((tn * 4 + lhi) ^ l7) << 4;
            {   // fn 0,1
                short8 bv0 = *(const short8*)(bsrc + (ln15) * 512 + sl);
                short8 bv1 = *(const short8*)(bsrc + (16 + ln15) * 512 + sl);
                __builtin_amdgcn_s_setprio(1);
                dst[0][0] = MFMA16(a0c, bv0, dst[0][0]);
                dst[1][0] = MFMA16(a1c, bv0, dst[1][0]);
                dst[0][1] = MFMA16(a0c, bv1, dst[0][1]);
                dst[1][1] = MFMA16(a1c, bv1, dst[1][1]);
                __builtin_amdgcn_s_setprio(0);
            }
            {   // fn 2
                short8 bv2 = *(const short8*)(bsrc + (32 + ln15) * 512 + sl);
                __builtin_amdgcn_s_setprio(1);
                dst[0][2] = MFMA16(a0c, bv2, dst[0][2]);
                dst[1][2] = MFMA16(a1c, bv2, dst[1][2]);
                __builtin_amdgcn_s_setprio(0);
            }
            a0c = a0m; a1c = a1m;
            if (tn < 6) { a0m = a0n; a1m = a1n; }
        }
    };

    {   // ---- phase 1: both GEMM1s (acc1 only live accumulator)
        f32x4 acc1[2][3];
        auto epi = [&](const float* b1e, const float* wsel, char* dst) {
#pragma unroll
            for (int fm = 0; fm < 2; ++fm) {
                int h0 = nbase + fm * 16 + lhi * 4;
                int hsl = h0 >> 3, hb = (h0 & 7) * 2;
                f32x4 b1f = *(const f32x4*)(b1e + h0);
#pragma unroll
                for (int fn = 0; fn < 3; ++fn) {
                    int row = fn * 16 + ln15;
                    float w = wsel[row];
                    u16x4 hv;
#pragma unroll
                    for (int i = 0; i < 4; ++i)
                        hv[i] = f2bf(gelu_f(acc1[fm][fn][i] + b1f[i]) * w);
                    *(u16x4*)(&dst[row * 512 + ((hsl ^ (row & 7)) << 4) + hb]) = hv;
                }
            }
        };
        // expert A: GEMM1A -> h1s
#pragma unroll
        for (int i = 0; i < 2; ++i)
#pragma unroll
            for (int j = 0; j < 3; ++j) acc1[i][j] = (f32x4)0.0f;
        gemm_phase(g1a, zls, acc1);
        epi(b1 + (ea << 8), wa_s, h1s);
        // expert B: GEMM1B (still reads zls)
#pragma unroll
        for (int i = 0; i < 2; ++i)
#pragma unroll
            for (int j = 0; j < 3; ++j) acc1[i][j] = (f32x4)0.0f;
        gemm_phase(g1b, zls, acc1);
        __syncthreads();               // all zls reads done; h1sA visible
        epi(b1 + (eb << 8), wb_s, zls);   // h1sB overwrites zls
        __syncthreads();               // h1sB visible
    }

    // ---- phase 2: combined GEMM2 (K=512) into acc (only live accumulator)
    f32x4 acc[2][3];
#pragma unroll
    for (int i = 0; i < 2; ++i)
#pragma unroll
        for (int j = 0; j < 3; ++j) acc[i][j] = (f32x4)0.0f;
    gemm_phase(g2a, h1s, acc);
    gemm_phase(g2b, zls, acc);

    // fold biases + residual (bf16 z from regs); per-row partial sums for LN
    float sA[3] = {0.0f, 0.0f, 0.0f};
    float sB[3] = {0.0f, 0.0f, 0.0f};
#pragma unroll
    for (int fm = 0; fm < 2; ++fm) {
        int d0 = nbase + fm * 16 + lhi * 4;
        f32x4 ba = *(const f32x4*)(b2 + (ea << 8) + d0);
        f32x4 bb = *(const f32x4*)(b2 + (eb << 8) + d0);
#pragma unroll
        for (int fn = 0; fn < 3; ++fn) {
            int row = fn * 16 + ln15;
            float wa = wa_s[row], wb = wb_s[row];
#pragma unroll
            for (int i = 0; i < 4; ++i) {
                float x = acc[fm][fn][i] + wa * ba[i] + wb * bb[i] + bf2f(zrv[fm][fn][i]);
                acc[fm][fn][i] = x;
                sA[fn] += x;
                sB[fn] += x * x;
            }
        }
    }
#pragma unroll
    for (int fn = 0; fn < 3; ++fn) {
        sA[fn] += __shfl_xor(sA[fn], 16, 64);
        sA[fn] += __shfl_xor(sA[fn], 32, 64);
        sB[fn] += __shfl_xor(sB[fn], 16, 64);
        sB[fn] += __shfl_xor(sB[fn], 32, 64);
    }
    if (lhi < 3) {
        float v1 = (lhi == 0) ? sA[0] : (lhi == 1) ? sA[1] : sA[2];
        float v2 = (lhi == 0) ? sB[0] : (lhi == 1) ? sB[1] : sB[2];
        int row = lhi * 16 + ln15;     // lane group lhi contributes fn = lhi
        ps[wv][row] = v1;
        pq[wv][row] = v2;
    }
    __syncthreads();

    float mu[3], rs[3];
#pragma unroll
    for (int fn = 0; fn < 3; ++fn) {
        int row = fn * 16 + ln15;
        float s = 0.0f, q = 0.0f;
#pragma unroll
        for (int j = 0; j < 8; ++j) { s += ps[j][row]; q += pq[j][row]; }
        float m = s * (1.0f / 256.0f);
        float var = q * (1.0f / 256.0f) - m * m;
        mu[fn] = m;
        rs[fn] = rsqrtf(var + 1e-5f);
    }
#pragma unroll
    for (int fm = 0; fm < 2; ++fm) {
        int d0 = nbase + fm * 16 + lhi * 4;
        f32x4 gm = *(const f32x4*)(ln_g + d0);
        f32x4 bt = *(const f32x4*)(ln_b + d0);
#pragma unroll
        for (int fn = 0; fn < 3; ++fn) {
            int row = fn * 16 + ln15;
            int g = ridx_s[row];
            if (g >= 0) {
                f32x4 yv;
#pragma unroll
                for (int i = 0; i < 4; ++i)
                    yv[i] = gm[i] * ((acc[fm][fn][i] - mu[fn]) * rs[fn]) + bt[i];
                __builtin_nontemporal_store(yv, (f32x4*)(y + (size_t)g * 256 + d0));
            }
        }
    }
}

extern "C" void kernel_launch(void* const* d_in, const int* in_sizes, int n_in,
                              void* d_out, int out_size, void* d_ws, size_t ws_size,
                              hipStream_t stream) {
    const float* z         = (const float*)d_in[0];
    const int*   ridx      = (const int*)d_in[1];
    const float* centroids = (const float*)d_in[2];
    const float* tau_raw   = (const float*)d_in[3];
    const float* W1        = (const float*)d_in[4];
    const float* b1        = (const float*)d_in[5];
    const float* W2        = (const float*)d_in[6];
    const float* b2        = (const float*)d_in[7];
    const float* lng       = (const float*)d_in[8];
    const float* lnb       = (const float*)d_in[9];
    float* out = (float*)d_out;

    unsigned short* W1s    = (unsigned short*)d_ws;                          // 512 KB
    unsigned short* W2s    = (unsigned short*)((char*)d_ws + 524288);        // 512 KB
    float*          wdense = (float*)((char*)d_ws + 1048576);                // 2 MB
    int*            perm   = (int*)((char*)d_ws + 3145728);                  // ~515 KB
    unsigned int*   ctr    = (unsigned int*)((char*)d_ws + 3672064);         // 96 B
    unsigned char*  prow   = (unsigned char*)((char*)d_ws + 3673088);        // 128 KB

    hipLaunchKernelGGL(prep_kernel, dim3(256), dim3(256), 0, stream, W1, W2, W1s, W2s, ctr);
    hipLaunchKernelGGL(gate_kernel, dim3(2048), dim3(256), 0, stream, z, ridx, centroids, tau_raw, wdense, prow, ctr);
    hipLaunchKernelGGL(offsets_kernel, dim3(1), dim3(64), 0, stream, ctr, perm, out);
    hipLaunchKernelGGL(scatter_kernel, dim3(512), dim3(256), 0, stream, prow, ctr, perm);
    hipLaunchKernelGGL(ffn_kernel, dim3(2744), dim3(512), 0, stream, z, W1s, W2s, b1, b2, wdense, lng, lnb, ctr, perm, out);
}